// Round 1
// baseline (2996.848 us; speedup 1.0000x reference)
//
#include <hip/hip_runtime.h>
#include <cfloat>
#include <cstddef>

// Problem constants (from reference setup_inputs)
#define N_A   4096
#define N_B   4096
#define G_A   3000   // n_genes_A
#define G_B   3000   // n_genes_B
#define NCA   30
#define NCB   25
#define KNBR  20

// ---------------------------------------------------------------------------
// norm_A = gene_dist.sum(axis=1) (row sums), zeros -> 1
__global__ __launch_bounds__(256) void row_sum_kernel(const float* __restrict__ G,
                                                      float* __restrict__ normA) {
    int row = blockIdx.x;
    __shared__ float red[256];
    float s = 0.f;
    for (int j = threadIdx.x; j < G_B; j += 256) s += G[(size_t)row * G_B + j];
    red[threadIdx.x] = s;
    __syncthreads();
    for (int off = 128; off > 0; off >>= 1) {
        if (threadIdx.x < off) red[threadIdx.x] += red[threadIdx.x + off];
        __syncthreads();
    }
    if (threadIdx.x == 0) {
        float v = red[0];
        normA[row] = (v == 0.f) ? 1.f : v;
    }
}

// norm_B = gene_dist.sum(axis=0) (col sums) -- two-pass partials (coalesced, parallel)
__global__ __launch_bounds__(256) void col_partial_kernel(const float* __restrict__ G,
                                                          float* __restrict__ part) {
    // grid (12, 25): columns via x, 120-row chunks via y
    int j = blockIdx.x * 256 + threadIdx.x;
    if (j >= G_B) return;
    int r0 = blockIdx.y * 120;
    float s = 0.f;
    for (int i = r0; i < r0 + 120; ++i) s += G[(size_t)i * G_B + j];
    part[(size_t)blockIdx.y * G_B + j] = s;
}

__global__ __launch_bounds__(256) void col_final_kernel(const float* __restrict__ part,
                                                        float* __restrict__ normB) {
    int j = blockIdx.x * 256 + threadIdx.x;
    if (j >= G_B) return;
    float s = 0.f;
    for (int c = 0; c < 25; ++c) s += part[(size_t)c * G_B + j];
    normB[j] = (s == 0.f) ? 1.f : s;
}

// ---------------------------------------------------------------------------
// out[i][j] = (sum_k X[i][k] * Gkj) / norm[j]
// TRANSB=false: Gkj = G[k][j]   (x_A @ gene_dist)
// TRANSB=true : Gkj = G[j][k]   (x_B @ gene_dist.T)
// 128x128 tile, BK=8 (3000 % 8 == 0), 256 threads, 8x8 micro-tile.
template <bool TRANSB>
__global__ __launch_bounds__(256) void impute_gemm(const float* __restrict__ X,
                                                   const float* __restrict__ G,
                                                   const float* __restrict__ norm,
                                                   float* __restrict__ out) {
    __shared__ float As[8][128];
    __shared__ float Bs[8][128];

    const int tid = threadIdx.x;
    const int col_base = blockIdx.x * 128;
    const int row_base = blockIdx.y * 128;

    const int tx = tid & 15;   // col group: cols tx*8 .. +7
    const int ty = tid >> 4;   // row group: rows ty*8 .. +7

    float acc[8][8] = {};

    const int a_row = tid >> 1;
    const int a_k   = (tid & 1) * 4;

    for (int k0 = 0; k0 < G_B; k0 += 8) {
        // stage A tile (128 rows x 8 k), transposed into LDS
        {
            float4 av = *(const float4*)(X + (size_t)(row_base + a_row) * G_B + k0 + a_k);
            As[a_k + 0][a_row] = av.x;
            As[a_k + 1][a_row] = av.y;
            As[a_k + 2][a_row] = av.z;
            As[a_k + 3][a_row] = av.w;
        }
        // stage B tile (8 k x 128 cols)
        if (!TRANSB) {
            const int bk = tid >> 5;            // 0..7
            const int bc = (tid & 31) * 4;      // 0..124
            float4 bv = {0.f, 0.f, 0.f, 0.f};
            if (col_base + bc < G_B)            // float4 all-or-nothing (3000 % 4 == 0)
                bv = *(const float4*)(G + (size_t)(k0 + bk) * G_B + col_base + bc);
            *(float4*)&Bs[bk][bc] = bv;
        } else {
            const int bj = tid >> 1;            // 0..127
            const int bk = (tid & 1) * 4;
            float4 bv = {0.f, 0.f, 0.f, 0.f};
            if (col_base + bj < G_B)
                bv = *(const float4*)(G + (size_t)(col_base + bj) * G_B + k0 + bk);
            Bs[bk + 0][bj] = bv.x;
            Bs[bk + 1][bj] = bv.y;
            Bs[bk + 2][bj] = bv.z;
            Bs[bk + 3][bj] = bv.w;
        }
        __syncthreads();

#pragma unroll
        for (int kk = 0; kk < 8; ++kk) {
            float4 a0 = *(const float4*)&As[kk][ty * 8];
            float4 a1 = *(const float4*)&As[kk][ty * 8 + 4];
            float4 b0 = *(const float4*)&Bs[kk][tx * 8];
            float4 b1 = *(const float4*)&Bs[kk][tx * 8 + 4];
            float a_[8] = {a0.x, a0.y, a0.z, a0.w, a1.x, a1.y, a1.z, a1.w};
            float b_[8] = {b0.x, b0.y, b0.z, b0.w, b1.x, b1.y, b1.z, b1.w};
#pragma unroll
            for (int i = 0; i < 8; ++i)
#pragma unroll
                for (int j = 0; j < 8; ++j) acc[i][j] += a_[i] * b_[j];
        }
        __syncthreads();
    }

    const int cg = col_base + tx * 8;
    if (cg < G_B) {   // 8-col group all-or-nothing (3000 % 8 == 0)
        float rn[8];
#pragma unroll
        for (int j = 0; j < 8; ++j) rn[j] = 1.0f / norm[cg + j];
#pragma unroll
        for (int i = 0; i < 8; ++i) {
            float4 o0 = {acc[i][0] * rn[0], acc[i][1] * rn[1], acc[i][2] * rn[2], acc[i][3] * rn[3]};
            float4 o1 = {acc[i][4] * rn[4], acc[i][5] * rn[5], acc[i][6] * rn[6], acc[i][7] * rn[7]};
            size_t o = (size_t)(row_base + ty * 8 + i) * G_B + cg;
            *(float4*)(out + o) = o0;
            *(float4*)(out + o + 4) = o1;
        }
    }
}

// ---------------------------------------------------------------------------
// Fused 2-layer MLP: emb = relu(relu([srcL|srcR] @ W1 + b1) @ W2 + b2)
// grid = 128 blocks: blocks 0..63 -> side A, 64..127 -> side B; 64 rows/block.
#define MLP_TK 24   // divides 3000

__global__ __launch_bounds__(256) void mlp_kernel(const float* __restrict__ xA,
                                                  const float* __restrict__ ximpA,
                                                  const float* __restrict__ ximpB,
                                                  const float* __restrict__ xB,
                                                  const float* __restrict__ W1,
                                                  const float* __restrict__ b1,
                                                  const float* __restrict__ W2,
                                                  const float* __restrict__ b2,
                                                  float* __restrict__ embA,
                                                  float* __restrict__ embB) {
    __shared__ float Xs[MLP_TK][64];   // [k][row]
    __shared__ float Ws[MLP_TK][64];   // [k][col]
    __shared__ float Hs[64][65];       // h1 [row][col], padded
    __shared__ float W2s[64][32];

    const int side = blockIdx.x >> 6;
    const int row0 = (blockIdx.x & 63) * 64;
    const float* srcL = side ? ximpB : xA;
    const float* srcR = side ? xB : ximpA;
    float* emb = side ? embB : embA;

    const int tid = threadIdx.x;

    // preload W2 (64x32)
    {
        const float4* src = (const float4*)W2;
        float4* dst = (float4*)&W2s[0][0];
        for (int i = tid; i < 512; i += 256) dst[i] = src[i];
    }

    const int tx = tid & 15;    // cols 4*tx .. +3
    const int ty = tid >> 4;    // rows 4*ty .. +3
    float acc[4][4] = {};

    const int lrow = tid >> 2;          // 0..63
    const int lk6  = (tid & 3) * 6;     // 0,6,12,18

    for (int k0 = 0; k0 < 6000; k0 += MLP_TK) {
        const float* src = (k0 < 3000) ? srcL : srcR;
        const int kbase = (k0 < 3000) ? k0 : (k0 - 3000);
        {
            const float* p = src + (size_t)(row0 + lrow) * 3000 + kbase + lk6;
#pragma unroll
            for (int e = 0; e < 6; ++e) Xs[lk6 + e][lrow] = p[e];
        }
        {
#pragma unroll
            for (int e = 0; e < 6; ++e) {
                int idx = tid * 6 + e;            // 0..1535
                int kk = idx >> 6, cc = idx & 63;
                Ws[kk][cc] = W1[(size_t)(k0 + kk) * 64 + cc];
            }
        }
        __syncthreads();
#pragma unroll
        for (int kk = 0; kk < MLP_TK; ++kk) {
            float4 a = *(const float4*)&Xs[kk][ty * 4];
            float4 w = *(const float4*)&Ws[kk][tx * 4];
            float a_[4] = {a.x, a.y, a.z, a.w};
            float w_[4] = {w.x, w.y, w.z, w.w};
#pragma unroll
            for (int i = 0; i < 4; ++i)
#pragma unroll
                for (int j = 0; j < 4; ++j) acc[i][j] += a_[i] * w_[j];
        }
        __syncthreads();
    }

    // bias + relu -> Hs
#pragma unroll
    for (int j = 0; j < 4; ++j) {
        float bj = b1[tx * 4 + j];
#pragma unroll
        for (int i = 0; i < 4; ++i) {
            float h = acc[i][j] + bj;
            Hs[ty * 4 + i][tx * 4 + j] = h > 0.f ? h : 0.f;
        }
    }
    __syncthreads();

    // layer 2: 64x64 @ 64x32
    const int c2 = tid & 31;
    const int rg = tid >> 5;   // 0..7 -> rows rg*8..+7
    float acc2[8] = {};
    for (int k = 0; k < 64; ++k) {
        float w = W2s[k][c2];
#pragma unroll
        for (int i = 0; i < 8; ++i) acc2[i] += Hs[rg * 8 + i][k] * w;
    }
    float bb = b2[c2];
#pragma unroll
    for (int i = 0; i < 8; ++i) {
        float h = acc2[i] + bb;
        emb[(size_t)(row0 + rg * 8 + i) * 32 + c2] = h > 0.f ? h : 0.f;
    }
}

// ---------------------------------------------------------------------------
__global__ __launch_bounds__(256) void sqnorm_kernel(const float* __restrict__ emb,
                                                     float* __restrict__ sq) {
    int i = blockIdx.x * 256 + threadIdx.x;
    if (i >= N_A) return;
    const float4* e = (const float4*)(emb + (size_t)i * 32);
    float s = 0.f;
#pragma unroll
    for (int q = 0; q < 8; ++q) {
        float4 v = e[q];
        s += v.x * v.x + v.y * v.y + v.z * v.z + v.w * v.w;
    }
    sq[i] = s;
}

// x_preds = emb @ Wc + bc
__global__ __launch_bounds__(256) void preds_kernel(const float* __restrict__ emb,
                                                    const float* __restrict__ Wc,
                                                    const float* __restrict__ bc,
                                                    float* __restrict__ out,
                                                    int ncls) {
    int idx = blockIdx.x * 256 + threadIdx.x;
    int row = idx / ncls, c = idx % ncls;
    const float* e = emb + (size_t)row * 32;
    float s = bc[c];
#pragma unroll
    for (int k = 0; k < 32; ++k) s += e[k] * Wc[k * ncls + c];
    out[idx] = s;
}

// ---------------------------------------------------------------------------
// Fused d2 + top-20 selection (rank on squared distance; sqrt is monotonic).
// One block per query row; buf[4096] of d2 in LDS; 20 x argmin with mark-taken.
__global__ __launch_bounds__(256) void topk_kernel(const float* __restrict__ embQ,
                                                   const float* __restrict__ sqQ,
                                                   const float* __restrict__ embC,
                                                   const float* __restrict__ sqC,
                                                   int* __restrict__ nn) {
    int q = blockIdx.x;
    __shared__ float buf[4096];
    __shared__ float rv[256];
    __shared__ int ri[256];

    float4 qv[8];
    const float4* eq = (const float4*)(embQ + (size_t)q * 32);
#pragma unroll
    for (int t = 0; t < 8; ++t) qv[t] = eq[t];
    float sqq = sqQ[q];

    for (int j = threadIdx.x; j < 4096; j += 256) {
        const float4* ec = (const float4*)(embC + (size_t)j * 32);
        float dot = 0.f;
#pragma unroll
        for (int t = 0; t < 8; ++t) {
            float4 c = ec[t];
            dot += qv[t].x * c.x + qv[t].y * c.y + qv[t].z * c.z + qv[t].w * c.w;
        }
        buf[j] = sqq + sqC[j] - 2.f * dot;
    }
    __syncthreads();

    for (int r = 0; r < KNBR; ++r) {
        float best = FLT_MAX;
        int bi = 0x7fffffff;
        for (int j = threadIdx.x; j < 4096; j += 256) {
            float v = buf[j];
            if (v < best) { best = v; bi = j; }   // ascending scan keeps lowest index on tie
        }
        rv[threadIdx.x] = best;
        ri[threadIdx.x] = bi;
        __syncthreads();
        for (int off = 128; off > 0; off >>= 1) {
            if (threadIdx.x < off) {
                float v2 = rv[threadIdx.x + off];
                int i2 = ri[threadIdx.x + off];
                if (v2 < rv[threadIdx.x] || (v2 == rv[threadIdx.x] && i2 < ri[threadIdx.x])) {
                    rv[threadIdx.x] = v2;
                    ri[threadIdx.x] = i2;
                }
            }
            __syncthreads();
        }
        if (threadIdx.x == 0) {
            nn[(size_t)q * KNBR + r] = ri[0];
            buf[ri[0]] = FLT_MAX;
        }
        __syncthreads();
    }
}

// ---------------------------------------------------------------------------
// Fused embedding-bag mean + MSE partial: partial[q] = sum_j (mean_t ximp[nn[q][t]][j] - x[q][j])^2
__global__ __launch_bounds__(256) void predloss_kernel(const int* __restrict__ nn,
                                                       const float* __restrict__ ximp,
                                                       const float* __restrict__ xtrue,
                                                       float* __restrict__ partial) {
    int q = blockIdx.x;
    __shared__ int nns[KNBR];
    __shared__ float red[256];
    if (threadIdx.x < KNBR) nns[threadIdx.x] = nn[(size_t)q * KNBR + threadIdx.x];
    __syncthreads();

    int nr[KNBR];
#pragma unroll
    for (int t = 0; t < KNBR; ++t) nr[t] = nns[t];

    const float inv = 1.0f / KNBR;
    float sse = 0.f;
    for (int v = threadIdx.x; v < 750; v += 256) {   // 750 float4 = 3000 cols
        float4 acc = {0.f, 0.f, 0.f, 0.f};
#pragma unroll
        for (int t = 0; t < KNBR; ++t) {
            const float4 w = *(const float4*)(ximp + (size_t)nr[t] * 3000 + v * 4);
            acc.x += w.x; acc.y += w.y; acc.z += w.z; acc.w += w.w;
        }
        const float4 xt = *(const float4*)(xtrue + (size_t)q * 3000 + v * 4);
        float dx = acc.x * inv - xt.x;
        float dy = acc.y * inv - xt.y;
        float dz = acc.z * inv - xt.z;
        float dw = acc.w * inv - xt.w;
        sse += dx * dx + dy * dy + dz * dz + dw * dw;
    }
    red[threadIdx.x] = sse;
    __syncthreads();
    for (int off = 128; off > 0; off >>= 1) {
        if (threadIdx.x < off) red[threadIdx.x] += red[threadIdx.x + off];
        __syncthreads();
    }
    if (threadIdx.x == 0) partial[q] = red[0];
}

__global__ __launch_bounds__(256) void loss_final_kernel(const float* __restrict__ pA,
                                                         const float* __restrict__ pB,
                                                         float* __restrict__ out) {
    __shared__ double red[256];
    double sa = 0.0, sb = 0.0;
    for (int i = threadIdx.x; i < 4096; i += 256) {
        sa += (double)pA[i];
        sb += (double)pB[i];
    }
    red[threadIdx.x] = sa;
    __syncthreads();
    for (int off = 128; off > 0; off >>= 1) {
        if (threadIdx.x < off) red[threadIdx.x] += red[threadIdx.x + off];
        __syncthreads();
    }
    double totA = red[0];
    __syncthreads();
    red[threadIdx.x] = sb;
    __syncthreads();
    for (int off = 128; off > 0; off >>= 1) {
        if (threadIdx.x < off) red[threadIdx.x] += red[threadIdx.x + off];
        __syncthreads();
    }
    if (threadIdx.x == 0) {
        double denom = 4096.0 * 3000.0;
        out[0] = (float)(totA / denom + red[0] / denom);
    }
}

// ---------------------------------------------------------------------------
extern "C" void kernel_launch(void* const* d_in, const int* in_sizes, int n_in,
                              void* d_out, int out_size, void* d_ws, size_t ws_size,
                              hipStream_t stream) {
    const float* x_A = (const float*)d_in[0];
    const float* x_B = (const float*)d_in[1];
    const float* G   = (const float*)d_in[2];
    const float* W1  = (const float*)d_in[3];
    const float* b1  = (const float*)d_in[4];
    const float* W2  = (const float*)d_in[5];
    const float* b2  = (const float*)d_in[6];
    const float* WcA = (const float*)d_in[7];
    const float* bcA = (const float*)d_in[8];
    const float* WcB = (const float*)d_in[9];
    const float* bcB = (const float*)d_in[10];

    float* outp = (float*)d_out;

    // workspace carve (~100.3 MB)
    float* ws = (float*)d_ws;
    float* ximpA = ws;  ws += (size_t)N_A * G_B;     // 12.288M
    float* ximpB = ws;  ws += (size_t)N_B * G_A;     // 12.288M
    float* normA = ws;  ws += G_A;
    float* normB = ws;  ws += G_B;
    float* colpart = ws; ws += 25 * G_B;             // col-sum partials
    float* embA = ws;   ws += (size_t)N_A * 32;
    float* embB = ws;   ws += (size_t)N_B * 32;
    float* sqA = ws;    ws += N_A;
    float* sqB = ws;    ws += N_B;
    float* partA = ws;  ws += N_A;
    float* partB = ws;  ws += N_B;
    int* nnA = (int*)ws; ws += (size_t)N_A * KNBR;
    int* nnB = (int*)ws; ws += (size_t)N_B * KNBR;

    // 1) normalizers
    row_sum_kernel<<<G_A, 256, 0, stream>>>(G, normA);
    col_partial_kernel<<<dim3(12, 25), 256, 0, stream>>>(G, colpart);
    col_final_kernel<<<12, 256, 0, stream>>>(colpart, normB);

    // 2) imputation GEMMs
    dim3 ggrid(24, 32);   // (3000/128 ceil, 4096/128)
    impute_gemm<false><<<ggrid, 256, 0, stream>>>(x_A, G, normB, ximpA);
    impute_gemm<true><<<ggrid, 256, 0, stream>>>(x_B, G, normA, ximpB);

    // 3) MLP -> embeddings (both sides in one launch)
    mlp_kernel<<<128, 256, 0, stream>>>(x_A, ximpA, ximpB, x_B, W1, b1, W2, b2, embA, embB);

    // 4) squared norms
    sqnorm_kernel<<<16, 256, 0, stream>>>(embA, sqA);
    sqnorm_kernel<<<16, 256, 0, stream>>>(embB, sqB);

    // 5) class predictions -> d_out
    preds_kernel<<<(N_A * NCA) / 256, 256, 0, stream>>>(embA, WcA, bcA, outp, NCA);
    preds_kernel<<<(N_B * NCB) / 256, 256, 0, stream>>>(embB, WcB, bcB, outp + (size_t)N_A * NCA, NCB);

    // 6) top-20 neighbors (rank on squared distance)
    topk_kernel<<<N_A, 256, 0, stream>>>(embA, sqA, embB, sqB, nnA);
    topk_kernel<<<N_B, 256, 0, stream>>>(embB, sqB, embA, sqA, nnB);

    // 7) fused gather-mean + MSE partials
    predloss_kernel<<<N_A, 256, 0, stream>>>(nnA, ximpB, x_A, partA);
    predloss_kernel<<<N_B, 256, 0, stream>>>(nnB, ximpA, x_B, partB);

    // 8) final deterministic loss reduction
    loss_final_kernel<<<1, 256, 0, stream>>>(partA, partB, outp + (size_t)N_A * NCA + (size_t)N_B * NCB);
}

// Round 2
// 1539.022 us; speedup vs baseline: 1.9472x; 1.9472x over previous
//
#include <hip/hip_runtime.h>
#include <cfloat>
#include <cstddef>

// Problem constants
#define N_A   4096
#define N_B   4096
#define G_A   3000
#define G_B   3000
#define NCA   30
#define NCB   25
#define KNBR  20
#define KPAD  3072   // K and N padded for MFMA tiles (multiple of 128)

typedef unsigned short u16;
typedef __bf16 bf16x8 __attribute__((ext_vector_type(8)));
typedef float f32x4 __attribute__((ext_vector_type(4)));
typedef __attribute__((address_space(1))) const void* as1_cvp;
typedef __attribute__((address_space(3))) void* as3_vp;

static __device__ __forceinline__ u16 f2bf(float f) {
    union { float f; unsigned u; } v; v.f = f;
    unsigned r = v.u + 0x7fffu + ((v.u >> 16) & 1u);   // RTNE
    return (u16)(r >> 16);
}

// ---------------------------------------------------------------------------
// normalizers
__global__ __launch_bounds__(256) void row_sum_kernel(const float* __restrict__ G,
                                                      float* __restrict__ normA) {
    int row = blockIdx.x;
    __shared__ float red[256];
    float s = 0.f;
    for (int j = threadIdx.x; j < G_B; j += 256) s += G[(size_t)row * G_B + j];
    red[threadIdx.x] = s;
    __syncthreads();
    for (int off = 128; off > 0; off >>= 1) {
        if (threadIdx.x < off) red[threadIdx.x] += red[threadIdx.x + off];
        __syncthreads();
    }
    if (threadIdx.x == 0) {
        float v = red[0];
        normA[row] = (v == 0.f) ? 1.f : v;
    }
}

__global__ __launch_bounds__(256) void col_partial_kernel(const float* __restrict__ G,
                                                          float* __restrict__ part) {
    int j = blockIdx.x * 256 + threadIdx.x;
    if (j >= G_B) return;
    int r0 = blockIdx.y * 120;
    float s = 0.f;
    for (int i = r0; i < r0 + 120; ++i) s += G[(size_t)i * G_B + j];
    part[(size_t)blockIdx.y * G_B + j] = s;
}

__global__ __launch_bounds__(256) void col_final_kernel(const float* __restrict__ part,
                                                        float* __restrict__ normB) {
    int j = blockIdx.x * 256 + threadIdx.x;
    if (j >= G_B) return;
    float s = 0.f;
    for (int c = 0; c < 25; ++c) s += part[(size_t)c * G_B + j];
    normB[j] = (s == 0.f) ? 1.f : s;
}

// ---------------------------------------------------------------------------
// f32 -> bf16 convert with zero padding to [out_rows][out_cols].
// Requires in_cols % 8 == 0 (3000 ok). grid*256 == out_rows*(out_cols/8).
__global__ __launch_bounds__(256) void convert_pad_kernel(const float* __restrict__ in,
                                                          u16* __restrict__ out,
                                                          int in_rows, int in_cols,
                                                          int out_cols) {
    int idx = blockIdx.x * 256 + threadIdx.x;
    int cpr = out_cols >> 3;
    int r = idx / cpr, c0 = (idx % cpr) << 3;
    u16 res[8] = {0, 0, 0, 0, 0, 0, 0, 0};
    if (r < in_rows && c0 + 8 <= in_cols) {
        float4 v0 = *(const float4*)(in + (size_t)r * in_cols + c0);
        float4 v1 = *(const float4*)(in + (size_t)r * in_cols + c0 + 4);
        res[0] = f2bf(v0.x); res[1] = f2bf(v0.y); res[2] = f2bf(v0.z); res[3] = f2bf(v0.w);
        res[4] = f2bf(v1.x); res[5] = f2bf(v1.y); res[6] = f2bf(v1.z); res[7] = f2bf(v1.w);
    }
    uint4 pack;
    pack.x = (unsigned)res[0] | ((unsigned)res[1] << 16);
    pack.y = (unsigned)res[2] | ((unsigned)res[3] << 16);
    pack.z = (unsigned)res[4] | ((unsigned)res[5] << 16);
    pack.w = (unsigned)res[6] | ((unsigned)res[7] << 16);
    *(uint4*)(out + (size_t)r * out_cols + c0) = pack;
}

// Gt[j][k] = bf16(G[k][j]), padded to [KPAD][KPAD]. grid (96,96), 256 thr.
__global__ __launch_bounds__(256) void transpose_convert_kernel(const float* __restrict__ G,
                                                                u16* __restrict__ Gt) {
    __shared__ float t[32][33];
    int j0 = blockIdx.x * 32, k0 = blockIdx.y * 32;
    int lx = threadIdx.x & 31, ly = threadIdx.x >> 5;   // 32 x 8
#pragma unroll
    for (int i = 0; i < 4; ++i) {
        int k = k0 + ly + i * 8, j = j0 + lx;
        t[ly + i * 8][lx] = (k < G_A && j < G_B) ? G[(size_t)k * G_B + j] : 0.f;
    }
    __syncthreads();
#pragma unroll
    for (int i = 0; i < 4; ++i) {
        int j = j0 + ly + i * 8, k = k0 + lx;
        Gt[(size_t)j * KPAD + k] = f2bf(t[lx][ly + i * 8]);
    }
}

// ---------------------------------------------------------------------------
// bf16 MFMA GEMM: out[i][j] = (sum_k A[i][k] * Bt[j][k]) / norm[j]
// A: [M][KPAD] bf16, Bt: [KPAD][KPAD] bf16 (row-major N x K), out: [M][3000] f32
// 128x128 tile, BK=64, 4 waves, 16x16x32 MFMA, global_load_lds w/ pre-swizzled src.
__global__ __launch_bounds__(256) void mfma_impute_gemm(const u16* __restrict__ A,
                                                        const u16* __restrict__ Bt,
                                                        const float* __restrict__ norm,
                                                        float* __restrict__ out) {
    __shared__ __align__(16) u16 lAs[128 * 64];
    __shared__ __align__(16) u16 lBs[128 * 64];

    const int tid = threadIdx.x;
    const int w = tid >> 6, lane = tid & 63;
    const int row_base = blockIdx.y * 128;
    const int col_base = blockIdx.x * 128;
    const int wr = (w >> 1) * 64, wc = (w & 1) * 64;

    f32x4 acc[4][4] = {};

    // staging geometry: slot = 16B chunk; tile = 128 rows x 8 slots.
    // load i of wave w covers linear slots (w*4+i)*64 + lane.
    int s_r[4], s_off[4];
#pragma unroll
    for (int i = 0; i < 4; ++i) {
        int slin = (w * 4 + i) * 64 + lane;
        int r = slin >> 3, s = slin & 7;
        s_r[i] = r;
        s_off[i] = (s ^ (r & 7)) * 8;   // pre-swizzled source chunk (elements)
    }

    for (int k0 = 0; k0 < KPAD; k0 += 64) {
#pragma unroll
        for (int i = 0; i < 4; ++i) {
            const u16* ga = A + (size_t)(row_base + s_r[i]) * KPAD + k0 + s_off[i];
            __builtin_amdgcn_global_load_lds((as1_cvp)ga,
                (as3_vp)(lAs + (size_t)(w * 4 + i) * 512), 16, 0, 0);
        }
#pragma unroll
        for (int i = 0; i < 4; ++i) {
            const u16* gb = Bt + (size_t)(col_base + s_r[i]) * KPAD + k0 + s_off[i];
            __builtin_amdgcn_global_load_lds((as1_cvp)gb,
                (as3_vp)(lBs + (size_t)(w * 4 + i) * 512), 16, 0, 0);
        }
        __syncthreads();

#pragma unroll
        for (int kk = 0; kk < 2; ++kk) {
            bf16x8 a[4], b[4];
#pragma unroll
            for (int m = 0; m < 4; ++m) {
                int row = wr + m * 16 + (lane & 15);
                int slot = (kk * 4 + (lane >> 4)) ^ (row & 7);
                a[m] = *(const bf16x8*)(lAs + row * 64 + slot * 8);
            }
#pragma unroll
            for (int n = 0; n < 4; ++n) {
                int row = wc + n * 16 + (lane & 15);
                int slot = (kk * 4 + (lane >> 4)) ^ (row & 7);
                b[n] = *(const bf16x8*)(lBs + row * 64 + slot * 8);
            }
#pragma unroll
            for (int m = 0; m < 4; ++m)
#pragma unroll
                for (int n = 0; n < 4; ++n)
                    acc[m][n] = __builtin_amdgcn_mfma_f32_16x16x32_bf16(a[m], b[n], acc[m][n], 0, 0, 0);
        }
        __syncthreads();
    }

    // epilogue: C/D layout col=lane&15, row=(lane>>4)*4+reg
#pragma unroll
    for (int n = 0; n < 4; ++n) {
        int col = col_base + wc + n * 16 + (lane & 15);
        if (col < G_B) {
            float rn = 1.0f / norm[col];
#pragma unroll
            for (int m = 0; m < 4; ++m) {
                int row = row_base + wr + m * 16 + (lane >> 4) * 4;
#pragma unroll
                for (int r = 0; r < 4; ++r)
                    out[(size_t)(row + r) * G_B + col] = acc[m][n][r] * rn;
            }
        }
    }
}

// ---------------------------------------------------------------------------
// Fallback f32 GEMM (round-1), used only if ws_size is too small for bf16 path.
template <bool TRANSB>
__global__ __launch_bounds__(256) void impute_gemm(const float* __restrict__ X,
                                                   const float* __restrict__ G,
                                                   const float* __restrict__ norm,
                                                   float* __restrict__ out) {
    __shared__ float As[8][128];
    __shared__ float Bs[8][128];
    const int tid = threadIdx.x;
    const int col_base = blockIdx.x * 128;
    const int row_base = blockIdx.y * 128;
    const int tx = tid & 15;
    const int ty = tid >> 4;
    float acc[8][8] = {};
    const int a_row = tid >> 1;
    const int a_k   = (tid & 1) * 4;
    for (int k0 = 0; k0 < G_B; k0 += 8) {
        {
            float4 av = *(const float4*)(X + (size_t)(row_base + a_row) * G_B + k0 + a_k);
            As[a_k + 0][a_row] = av.x;
            As[a_k + 1][a_row] = av.y;
            As[a_k + 2][a_row] = av.z;
            As[a_k + 3][a_row] = av.w;
        }
        if (!TRANSB) {
            const int bk = tid >> 5;
            const int bc = (tid & 31) * 4;
            float4 bv = {0.f, 0.f, 0.f, 0.f};
            if (col_base + bc < G_B)
                bv = *(const float4*)(G + (size_t)(k0 + bk) * G_B + col_base + bc);
            *(float4*)&Bs[bk][bc] = bv;
        } else {
            const int bj = tid >> 1;
            const int bk = (tid & 1) * 4;
            float4 bv = {0.f, 0.f, 0.f, 0.f};
            if (col_base + bj < G_B)
                bv = *(const float4*)(G + (size_t)(col_base + bj) * G_B + k0 + bk);
            Bs[bk + 0][bj] = bv.x;
            Bs[bk + 1][bj] = bv.y;
            Bs[bk + 2][bj] = bv.z;
            Bs[bk + 3][bj] = bv.w;
        }
        __syncthreads();
#pragma unroll
        for (int kk = 0; kk < 8; ++kk) {
            float4 a0 = *(const float4*)&As[kk][ty * 8];
            float4 a1 = *(const float4*)&As[kk][ty * 8 + 4];
            float4 b0 = *(const float4*)&Bs[kk][tx * 8];
            float4 b1 = *(const float4*)&Bs[kk][tx * 8 + 4];
            float a_[8] = {a0.x, a0.y, a0.z, a0.w, a1.x, a1.y, a1.z, a1.w};
            float b_[8] = {b0.x, b0.y, b0.z, b0.w, b1.x, b1.y, b1.z, b1.w};
#pragma unroll
            for (int i = 0; i < 8; ++i)
#pragma unroll
                for (int j = 0; j < 8; ++j) acc[i][j] += a_[i] * b_[j];
        }
        __syncthreads();
    }
    const int cg = col_base + tx * 8;
    if (cg < G_B) {
        float rn[8];
#pragma unroll
        for (int j = 0; j < 8; ++j) rn[j] = 1.0f / norm[cg + j];
#pragma unroll
        for (int i = 0; i < 8; ++i) {
            float4 o0 = {acc[i][0] * rn[0], acc[i][1] * rn[1], acc[i][2] * rn[2], acc[i][3] * rn[3]};
            float4 o1 = {acc[i][4] * rn[4], acc[i][5] * rn[5], acc[i][6] * rn[6], acc[i][7] * rn[7]};
            size_t o = (size_t)(row_base + ty * 8 + i) * G_B + cg;
            *(float4*)(out + o) = o0;
            *(float4*)(out + o + 4) = o1;
        }
    }
}

// ---------------------------------------------------------------------------
#define MLP_TK 24

__global__ __launch_bounds__(256) void mlp_kernel(const float* __restrict__ xA,
                                                  const float* __restrict__ ximpA,
                                                  const float* __restrict__ ximpB,
                                                  const float* __restrict__ xB,
                                                  const float* __restrict__ W1,
                                                  const float* __restrict__ b1,
                                                  const float* __restrict__ W2,
                                                  const float* __restrict__ b2,
                                                  float* __restrict__ embA,
                                                  float* __restrict__ embB) {
    __shared__ float Xs[MLP_TK][64];
    __shared__ float Ws[MLP_TK][64];
    __shared__ float Hs[64][65];
    __shared__ float W2s[64][32];

    const int side = blockIdx.x >> 6;
    const int row0 = (blockIdx.x & 63) * 64;
    const float* srcL = side ? ximpB : xA;
    const float* srcR = side ? xB : ximpA;
    float* emb = side ? embB : embA;

    const int tid = threadIdx.x;
    {
        const float4* src = (const float4*)W2;
        float4* dst = (float4*)&W2s[0][0];
        for (int i = tid; i < 512; i += 256) dst[i] = src[i];
    }

    const int tx = tid & 15;
    const int ty = tid >> 4;
    float acc[4][4] = {};
    const int lrow = tid >> 2;
    const int lk6  = (tid & 3) * 6;

    for (int k0 = 0; k0 < 6000; k0 += MLP_TK) {
        const float* src = (k0 < 3000) ? srcL : srcR;
        const int kbase = (k0 < 3000) ? k0 : (k0 - 3000);
        {
            const float* p = src + (size_t)(row0 + lrow) * 3000 + kbase + lk6;
#pragma unroll
            for (int e = 0; e < 6; ++e) Xs[lk6 + e][lrow] = p[e];
        }
        {
#pragma unroll
            for (int e = 0; e < 6; ++e) {
                int idx = tid * 6 + e;
                int kk = idx >> 6, cc = idx & 63;
                Ws[kk][cc] = W1[(size_t)(k0 + kk) * 64 + cc];
            }
        }
        __syncthreads();
#pragma unroll
        for (int kk = 0; kk < MLP_TK; ++kk) {
            float4 a = *(const float4*)&Xs[kk][ty * 4];
            float4 wv = *(const float4*)&Ws[kk][tx * 4];
            float a_[4] = {a.x, a.y, a.z, a.w};
            float w_[4] = {wv.x, wv.y, wv.z, wv.w};
#pragma unroll
            for (int i = 0; i < 4; ++i)
#pragma unroll
                for (int j = 0; j < 4; ++j) acc[i][j] += a_[i] * w_[j];
        }
        __syncthreads();
    }

#pragma unroll
    for (int j = 0; j < 4; ++j) {
        float bj = b1[tx * 4 + j];
#pragma unroll
        for (int i = 0; i < 4; ++i) {
            float h = acc[i][j] + bj;
            Hs[ty * 4 + i][tx * 4 + j] = h > 0.f ? h : 0.f;
        }
    }
    __syncthreads();

    const int c2 = tid & 31;
    const int rg = tid >> 5;
    float acc2[8] = {};
    for (int k = 0; k < 64; ++k) {
        float wv = W2s[k][c2];
#pragma unroll
        for (int i = 0; i < 8; ++i) acc2[i] += Hs[rg * 8 + i][k] * wv;
    }
    float bb = b2[c2];
#pragma unroll
    for (int i = 0; i < 8; ++i) {
        float h = acc2[i] + bb;
        emb[(size_t)(row0 + rg * 8 + i) * 32 + c2] = h > 0.f ? h : 0.f;
    }
}

// ---------------------------------------------------------------------------
__global__ __launch_bounds__(256) void sqnorm_kernel(const float* __restrict__ emb,
                                                     float* __restrict__ sq) {
    int i = blockIdx.x * 256 + threadIdx.x;
    if (i >= N_A) return;
    const float4* e = (const float4*)(emb + (size_t)i * 32);
    float s = 0.f;
#pragma unroll
    for (int q = 0; q < 8; ++q) {
        float4 v = e[q];
        s += v.x * v.x + v.y * v.y + v.z * v.z + v.w * v.w;
    }
    sq[i] = s;
}

__global__ __launch_bounds__(256) void preds_kernel(const float* __restrict__ emb,
                                                    const float* __restrict__ Wc,
                                                    const float* __restrict__ bc,
                                                    float* __restrict__ out,
                                                    int ncls) {
    int idx = blockIdx.x * 256 + threadIdx.x;
    int row = idx / ncls, c = idx % ncls;
    const float* e = emb + (size_t)row * 32;
    float s = bc[c];
#pragma unroll
    for (int k = 0; k < 32; ++k) s += e[k] * Wc[k * ncls + c];
    out[idx] = s;
}

// ---------------------------------------------------------------------------
__global__ __launch_bounds__(256) void topk_kernel(const float* __restrict__ embQ,
                                                   const float* __restrict__ sqQ,
                                                   const float* __restrict__ embC,
                                                   const float* __restrict__ sqC,
                                                   int* __restrict__ nn) {
    int q = blockIdx.x;
    __shared__ float buf[4096];
    __shared__ float rv[256];
    __shared__ int ri[256];

    float4 qv[8];
    const float4* eq = (const float4*)(embQ + (size_t)q * 32);
#pragma unroll
    for (int t = 0; t < 8; ++t) qv[t] = eq[t];
    float sqq = sqQ[q];

    for (int j = threadIdx.x; j < 4096; j += 256) {
        const float4* ec = (const float4*)(embC + (size_t)j * 32);
        float dot = 0.f;
#pragma unroll
        for (int t = 0; t < 8; ++t) {
            float4 c = ec[t];
            dot += qv[t].x * c.x + qv[t].y * c.y + qv[t].z * c.z + qv[t].w * c.w;
        }
        buf[j] = sqq + sqC[j] - 2.f * dot;
    }
    __syncthreads();

    for (int r = 0; r < KNBR; ++r) {
        float best = FLT_MAX;
        int bi = 0x7fffffff;
        for (int j = threadIdx.x; j < 4096; j += 256) {
            float v = buf[j];
            if (v < best) { best = v; bi = j; }
        }
        rv[threadIdx.x] = best;
        ri[threadIdx.x] = bi;
        __syncthreads();
        for (int off = 128; off > 0; off >>= 1) {
            if (threadIdx.x < off) {
                float v2 = rv[threadIdx.x + off];
                int i2 = ri[threadIdx.x + off];
                if (v2 < rv[threadIdx.x] || (v2 == rv[threadIdx.x] && i2 < ri[threadIdx.x])) {
                    rv[threadIdx.x] = v2;
                    ri[threadIdx.x] = i2;
                }
            }
            __syncthreads();
        }
        if (threadIdx.x == 0) {
            nn[(size_t)q * KNBR + r] = ri[0];
            buf[ri[0]] = FLT_MAX;
        }
        __syncthreads();
    }
}

// ---------------------------------------------------------------------------
__global__ __launch_bounds__(256) void predloss_kernel(const int* __restrict__ nn,
                                                       const float* __restrict__ ximp,
                                                       const float* __restrict__ xtrue,
                                                       float* __restrict__ partial) {
    int q = blockIdx.x;
    __shared__ int nns[KNBR];
    __shared__ float red[256];
    if (threadIdx.x < KNBR) nns[threadIdx.x] = nn[(size_t)q * KNBR + threadIdx.x];
    __syncthreads();

    int nr[KNBR];
#pragma unroll
    for (int t = 0; t < KNBR; ++t) nr[t] = nns[t];

    const float inv = 1.0f / KNBR;
    float sse = 0.f;
    for (int v = threadIdx.x; v < 750; v += 256) {
        float4 acc = {0.f, 0.f, 0.f, 0.f};
#pragma unroll
        for (int t = 0; t < KNBR; ++t) {
            const float4 w = *(const float4*)(ximp + (size_t)nr[t] * 3000 + v * 4);
            acc.x += w.x; acc.y += w.y; acc.z += w.z; acc.w += w.w;
        }
        const float4 xt = *(const float4*)(xtrue + (size_t)q * 3000 + v * 4);
        float dx = acc.x * inv - xt.x;
        float dy = acc.y * inv - xt.y;
        float dz = acc.z * inv - xt.z;
        float dw = acc.w * inv - xt.w;
        sse += dx * dx + dy * dy + dz * dz + dw * dw;
    }
    red[threadIdx.x] = sse;
    __syncthreads();
    for (int off = 128; off > 0; off >>= 1) {
        if (threadIdx.x < off) red[threadIdx.x] += red[threadIdx.x + off];
        __syncthreads();
    }
    if (threadIdx.x == 0) partial[q] = red[0];
}

__global__ __launch_bounds__(256) void loss_final_kernel(const float* __restrict__ pA,
                                                         const float* __restrict__ pB,
                                                         float* __restrict__ out) {
    __shared__ double red[256];
    double sa = 0.0, sb = 0.0;
    for (int i = threadIdx.x; i < 4096; i += 256) {
        sa += (double)pA[i];
        sb += (double)pB[i];
    }
    red[threadIdx.x] = sa;
    __syncthreads();
    for (int off = 128; off > 0; off >>= 1) {
        if (threadIdx.x < off) red[threadIdx.x] += red[threadIdx.x + off];
        __syncthreads();
    }
    double totA = red[0];
    __syncthreads();
    red[threadIdx.x] = sb;
    __syncthreads();
    for (int off = 128; off > 0; off >>= 1) {
        if (threadIdx.x < off) red[threadIdx.x] += red[threadIdx.x + off];
        __syncthreads();
    }
    if (threadIdx.x == 0) {
        double denom = 4096.0 * 3000.0;
        out[0] = (float)(totA / denom + red[0] / denom);
    }
}

// ---------------------------------------------------------------------------
extern "C" void kernel_launch(void* const* d_in, const int* in_sizes, int n_in,
                              void* d_out, int out_size, void* d_ws, size_t ws_size,
                              hipStream_t stream) {
    const float* x_A = (const float*)d_in[0];
    const float* x_B = (const float*)d_in[1];
    const float* G   = (const float*)d_in[2];
    const float* W1  = (const float*)d_in[3];
    const float* b1  = (const float*)d_in[4];
    const float* W2  = (const float*)d_in[5];
    const float* b2  = (const float*)d_in[6];
    const float* WcA = (const float*)d_in[7];
    const float* bcA = (const float*)d_in[8];
    const float* WcB = (const float*)d_in[9];
    const float* bcB = (const float*)d_in[10];

    float* outp = (float*)d_out;

    // byte-carved workspace with 256B alignment
    size_t off = 0;
    char* base = (char*)d_ws;
    auto carve = [&](size_t bytes) -> void* {
        void* p = base + off;
        off = (off + bytes + 255) & ~(size_t)255;
        return p;
    };
    float* ximpA = (float*)carve((size_t)N_A * G_B * 4);
    float* ximpB = (float*)carve((size_t)N_B * G_A * 4);
    float* normA = (float*)carve(G_A * 4);
    float* normB = (float*)carve(G_B * 4);
    float* colpart = (float*)carve(25 * G_B * 4);
    float* embA = (float*)carve((size_t)N_A * 32 * 4);
    float* embB = (float*)carve((size_t)N_B * 32 * 4);
    float* sqA = (float*)carve(N_A * 4);
    float* sqB = (float*)carve(N_B * 4);
    float* partA = (float*)carve(N_A * 4);
    float* partB = (float*)carve(N_B * 4);
    int* nnA = (int*)carve((size_t)N_A * KNBR * 4);
    int* nnB = (int*)carve((size_t)N_B * KNBR * 4);
    size_t base_needed = off;
    u16* xAbf = (u16*)carve((size_t)N_A * KPAD * 2);
    u16* xBbf = (u16*)carve((size_t)N_B * KPAD * 2);
    u16* Gbf  = (u16*)carve((size_t)KPAD * KPAD * 2);
    u16* Gtbf = (u16*)carve((size_t)KPAD * KPAD * 2);
    size_t bf16_needed = off;

    const bool use_mfma = (ws_size >= bf16_needed);

    // 1) normalizers
    row_sum_kernel<<<G_A, 256, 0, stream>>>(G, normA);
    col_partial_kernel<<<dim3(12, 25), 256, 0, stream>>>(G, colpart);
    col_final_kernel<<<12, 256, 0, stream>>>(colpart, normB);

    // 2) imputation GEMMs
    if (use_mfma) {
        // bf16 conversions (padded)
        convert_pad_kernel<<<(N_A * (KPAD / 8)) / 256, 256, 0, stream>>>(x_A, xAbf, N_A, G_A, KPAD);
        convert_pad_kernel<<<(N_B * (KPAD / 8)) / 256, 256, 0, stream>>>(x_B, xBbf, N_B, G_B, KPAD);
        convert_pad_kernel<<<(KPAD * (KPAD / 8)) / 256, 256, 0, stream>>>(G, Gbf, G_A, G_B, KPAD);
        transpose_convert_kernel<<<dim3(96, 96), 256, 0, stream>>>(G, Gtbf);

        dim3 ggrid(KPAD / 128, N_A / 128);   // (24, 32)
        mfma_impute_gemm<<<ggrid, 256, 0, stream>>>(xAbf, Gtbf, normB, ximpA);
        mfma_impute_gemm<<<ggrid, 256, 0, stream>>>(xBbf, Gbf, normA, ximpB);
    } else {
        dim3 ggrid(24, 32);
        impute_gemm<false><<<ggrid, 256, 0, stream>>>(x_A, G, normB, ximpA);
        impute_gemm<true><<<ggrid, 256, 0, stream>>>(x_B, G, normA, ximpB);
    }

    // 3) MLP -> embeddings
    mlp_kernel<<<128, 256, 0, stream>>>(x_A, ximpA, ximpB, x_B, W1, b1, W2, b2, embA, embB);

    // 4) squared norms
    sqnorm_kernel<<<16, 256, 0, stream>>>(embA, sqA);
    sqnorm_kernel<<<16, 256, 0, stream>>>(embB, sqB);

    // 5) class predictions -> d_out
    preds_kernel<<<(N_A * NCA) / 256, 256, 0, stream>>>(embA, WcA, bcA, outp, NCA);
    preds_kernel<<<(N_B * NCB) / 256, 256, 0, stream>>>(embB, WcB, bcB, outp + (size_t)N_A * NCA, NCB);

    // 6) top-20 neighbors
    topk_kernel<<<N_A, 256, 0, stream>>>(embA, sqA, embB, sqB, nnA);
    topk_kernel<<<N_B, 256, 0, stream>>>(embB, sqB, embA, sqA, nnB);

    // 7) fused gather-mean + MSE partials
    predloss_kernel<<<N_A, 256, 0, stream>>>(nnA, ximpB, x_A, partA);
    predloss_kernel<<<N_B, 256, 0, stream>>>(nnB, ximpA, x_B, partB);

    // 8) final loss
    loss_final_kernel<<<1, 256, 0, stream>>>(partA, partB, outp + (size_t)N_A * NCA + (size_t)N_B * NCB);

    (void)base_needed; (void)in_sizes; (void)n_in; (void)out_size; (void)ws_size;
}

// Round 3
// 1188.324 us; speedup vs baseline: 2.5219x; 1.2951x over previous
//
#include <hip/hip_runtime.h>
#include <cfloat>
#include <cstddef>

// Problem constants
#define N_A   4096
#define N_B   4096
#define G_A   3000
#define G_B   3000
#define NCA   30
#define NCB   25
#define KNBR  20
#define KPAD  3072   // K/N padding for MFMA tiles (multiple of 128)
#define KMLP  6144   // padded MLP K ( = 2*KPAD )

typedef unsigned short u16;
typedef __bf16 bf16x8 __attribute__((ext_vector_type(8)));
typedef float f32x4 __attribute__((ext_vector_type(4)));
typedef __attribute__((address_space(1))) const void* as1_cvp;
typedef __attribute__((address_space(3))) void* as3_vp;

static __device__ __forceinline__ u16 f2bf(float f) {
    union { float f; unsigned u; } v; v.f = f;
    unsigned r = v.u + 0x7fffu + ((v.u >> 16) & 1u);   // RTNE
    return (u16)(r >> 16);
}

// ---------------------------------------------------------------------------
// normalizers
__global__ __launch_bounds__(256) void row_sum_kernel(const float* __restrict__ G,
                                                      float* __restrict__ normA) {
    int row = blockIdx.x;
    __shared__ float red[256];
    float s = 0.f;
    for (int j = threadIdx.x; j < G_B; j += 256) s += G[(size_t)row * G_B + j];
    red[threadIdx.x] = s;
    __syncthreads();
    for (int off = 128; off > 0; off >>= 1) {
        if (threadIdx.x < off) red[threadIdx.x] += red[threadIdx.x + off];
        __syncthreads();
    }
    if (threadIdx.x == 0) {
        float v = red[0];
        normA[row] = (v == 0.f) ? 1.f : v;
    }
}

__global__ __launch_bounds__(256) void col_partial_kernel(const float* __restrict__ G,
                                                          float* __restrict__ part) {
    int j = blockIdx.x * 256 + threadIdx.x;
    if (j >= G_B) return;
    int r0 = blockIdx.y * 120;
    float s = 0.f;
    for (int i = r0; i < r0 + 120; ++i) s += G[(size_t)i * G_B + j];
    part[(size_t)blockIdx.y * G_B + j] = s;
}

__global__ __launch_bounds__(256) void col_final_kernel(const float* __restrict__ part,
                                                        float* __restrict__ normB) {
    int j = blockIdx.x * 256 + threadIdx.x;
    if (j >= G_B) return;
    float s = 0.f;
    for (int c = 0; c < 25; ++c) s += part[(size_t)c * G_B + j];
    normB[j] = (s == 0.f) ? 1.f : s;
}

// ---------------------------------------------------------------------------
// f32 -> bf16 convert with zero padding
__global__ __launch_bounds__(256) void convert_pad_kernel(const float* __restrict__ in,
                                                          u16* __restrict__ out,
                                                          int in_rows, int in_cols,
                                                          int out_cols) {
    int idx = blockIdx.x * 256 + threadIdx.x;
    int cpr = out_cols >> 3;
    int r = idx / cpr, c0 = (idx % cpr) << 3;
    u16 res[8] = {0, 0, 0, 0, 0, 0, 0, 0};
    if (r < in_rows && c0 + 8 <= in_cols) {
        float4 v0 = *(const float4*)(in + (size_t)r * in_cols + c0);
        float4 v1 = *(const float4*)(in + (size_t)r * in_cols + c0 + 4);
        res[0] = f2bf(v0.x); res[1] = f2bf(v0.y); res[2] = f2bf(v0.z); res[3] = f2bf(v0.w);
        res[4] = f2bf(v1.x); res[5] = f2bf(v1.y); res[6] = f2bf(v1.z); res[7] = f2bf(v1.w);
    }
    uint4 pack;
    pack.x = (unsigned)res[0] | ((unsigned)res[1] << 16);
    pack.y = (unsigned)res[2] | ((unsigned)res[3] << 16);
    pack.z = (unsigned)res[4] | ((unsigned)res[5] << 16);
    pack.w = (unsigned)res[6] | ((unsigned)res[7] << 16);
    *(uint4*)(out + (size_t)r * out_cols + c0) = pack;
}

// Gt[j][k] = bf16(G[k][j]) padded to [KPAD][KPAD]
__global__ __launch_bounds__(256) void transpose_convert_kernel(const float* __restrict__ G,
                                                                u16* __restrict__ Gt) {
    __shared__ float t[32][33];
    int j0 = blockIdx.x * 32, k0 = blockIdx.y * 32;
    int lx = threadIdx.x & 31, ly = threadIdx.x >> 5;
#pragma unroll
    for (int i = 0; i < 4; ++i) {
        int k = k0 + ly + i * 8, j = j0 + lx;
        t[ly + i * 8][lx] = (k < G_A && j < G_B) ? G[(size_t)k * G_B + j] : 0.f;
    }
    __syncthreads();
#pragma unroll
    for (int i = 0; i < 4; ++i) {
        int j = j0 + ly + i * 8, k = k0 + lx;
        Gt[(size_t)j * KPAD + k] = f2bf(t[lx][ly + i * 8]);
    }
}

// W1 [6000][64] f32 -> W1t [64][KMLP] bf16 (seg0: rows 0..2999 @ k 0..3071,
// seg1: rows 3000..5999 @ k 3072..6143, pads zero)
__global__ __launch_bounds__(256) void w1t_kernel(const float* __restrict__ W1,
                                                  u16* __restrict__ W1t) {
    int idx = blockIdx.x * 256 + threadIdx.x;     // 64*6144 elems
    int n = idx / KMLP, kp = idx % KMLP;
    int seg = kp >= KPAD;
    int k = kp - (seg ? KPAD : 0);
    float v = (k < 3000) ? W1[(size_t)(seg * 3000 + k) * 64 + n] : 0.f;
    W1t[(size_t)n * KMLP + kp] = f2bf(v);
}

// ---------------------------------------------------------------------------
// bf16 MFMA GEMM: out[i][j] = (sum_k A[i][k] * Bt[j][k]) / norm[j]
// Dual-writes f32 [M][3000] and bf16 [M][KPAD] (pads zeroed).
__global__ __launch_bounds__(256) void mfma_impute_gemm(const u16* __restrict__ A,
                                                        const u16* __restrict__ Bt,
                                                        const float* __restrict__ norm,
                                                        float* __restrict__ out,
                                                        u16* __restrict__ outbf) {
    __shared__ __align__(16) u16 lAs[128 * 64];
    __shared__ __align__(16) u16 lBs[128 * 64];

    const int tid = threadIdx.x;
    const int w = tid >> 6, lane = tid & 63;
    const int row_base = blockIdx.y * 128;
    const int col_base = blockIdx.x * 128;
    const int wr = (w >> 1) * 64, wc = (w & 1) * 64;

    f32x4 acc[4][4] = {};

    int s_r[4], s_off[4];
#pragma unroll
    for (int i = 0; i < 4; ++i) {
        int slin = (w * 4 + i) * 64 + lane;
        int r = slin >> 3, s = slin & 7;
        s_r[i] = r;
        s_off[i] = (s ^ (r & 7)) * 8;
    }

    for (int k0 = 0; k0 < KPAD; k0 += 64) {
#pragma unroll
        for (int i = 0; i < 4; ++i) {
            const u16* ga = A + (size_t)(row_base + s_r[i]) * KPAD + k0 + s_off[i];
            __builtin_amdgcn_global_load_lds((as1_cvp)ga,
                (as3_vp)(lAs + (size_t)(w * 4 + i) * 512), 16, 0, 0);
        }
#pragma unroll
        for (int i = 0; i < 4; ++i) {
            const u16* gb = Bt + (size_t)(col_base + s_r[i]) * KPAD + k0 + s_off[i];
            __builtin_amdgcn_global_load_lds((as1_cvp)gb,
                (as3_vp)(lBs + (size_t)(w * 4 + i) * 512), 16, 0, 0);
        }
        __syncthreads();

#pragma unroll
        for (int kk = 0; kk < 2; ++kk) {
            bf16x8 a[4], b[4];
#pragma unroll
            for (int m = 0; m < 4; ++m) {
                int row = wr + m * 16 + (lane & 15);
                int slot = (kk * 4 + (lane >> 4)) ^ (row & 7);
                a[m] = *(const bf16x8*)(lAs + row * 64 + slot * 8);
            }
#pragma unroll
            for (int n = 0; n < 4; ++n) {
                int row = wc + n * 16 + (lane & 15);
                int slot = (kk * 4 + (lane >> 4)) ^ (row & 7);
                b[n] = *(const bf16x8*)(lBs + row * 64 + slot * 8);
            }
#pragma unroll
            for (int m = 0; m < 4; ++m)
#pragma unroll
                for (int n = 0; n < 4; ++n)
                    acc[m][n] = __builtin_amdgcn_mfma_f32_16x16x32_bf16(a[m], b[n], acc[m][n], 0, 0, 0);
        }
        __syncthreads();
    }

#pragma unroll
    for (int n = 0; n < 4; ++n) {
        int col = col_base + wc + n * 16 + (lane & 15);
        bool valid = col < G_B;
        float rn = valid ? 1.0f / norm[col] : 0.f;
#pragma unroll
        for (int m = 0; m < 4; ++m) {
            int row = row_base + wr + m * 16 + (lane >> 4) * 4;
#pragma unroll
            for (int r = 0; r < 4; ++r) {
                float v = acc[m][n][r] * rn;
                if (valid) out[(size_t)(row + r) * G_B + col] = v;
                outbf[(size_t)(row + r) * KPAD + col] = f2bf(v);
            }
        }
    }
}

// ---------------------------------------------------------------------------
// MLP layer 1 (bf16 MFMA, K-split): partial[chunk][grow][col] over K-chunks of 1536
__global__ __launch_bounds__(256) void mlp1_kernel(const u16* __restrict__ xAbf,
                                                   const u16* __restrict__ ximpAbf,
                                                   const u16* __restrict__ ximpBbf,
                                                   const u16* __restrict__ xBbf,
                                                   const u16* __restrict__ W1t,
                                                   float* __restrict__ partial) {
    const int chunk = blockIdx.x;          // 0..3
    const int rb = blockIdx.y;             // 0..127 (64 rows each; 0..63 A, 64..127 B)
    const int side = rb >> 6;
    const int r0 = (rb & 63) * 64;
    const int seg = chunk >> 1;
    const u16* src = side ? (seg ? xBbf : ximpBbf) : (seg ? ximpAbf : xAbf);
    const int k0base = (chunk & 1) * 1536;

    __shared__ __align__(16) u16 lAs[64 * 64];
    __shared__ __align__(16) u16 lBs[64 * 64];

    const int tid = threadIdx.x;
    const int w = tid >> 6, lane = tid & 63;

    int s_r[2], s_off[2];
#pragma unroll
    for (int i = 0; i < 2; ++i) {
        int slin = (w * 2 + i) * 64 + lane;
        int r = slin >> 3, s = slin & 7;
        s_r[i] = r;
        s_off[i] = (s ^ (r & 7)) * 8;
    }

    f32x4 acc[4] = {};

    for (int k0 = 0; k0 < 1536; k0 += 64) {
#pragma unroll
        for (int i = 0; i < 2; ++i) {
            const u16* ga = src + (size_t)(r0 + s_r[i]) * KPAD + k0base + k0 + s_off[i];
            __builtin_amdgcn_global_load_lds((as1_cvp)ga,
                (as3_vp)(lAs + (size_t)(w * 2 + i) * 512), 16, 0, 0);
        }
#pragma unroll
        for (int i = 0; i < 2; ++i) {
            const u16* gb = W1t + (size_t)s_r[i] * KMLP + chunk * 1536 + k0 + s_off[i];
            __builtin_amdgcn_global_load_lds((as1_cvp)gb,
                (as3_vp)(lBs + (size_t)(w * 2 + i) * 512), 16, 0, 0);
        }
        __syncthreads();

#pragma unroll
        for (int kk = 0; kk < 2; ++kk) {
            int arow = w * 16 + (lane & 15);
            int aslot = (kk * 4 + (lane >> 4)) ^ (arow & 7);
            bf16x8 a = *(const bf16x8*)(lAs + arow * 64 + aslot * 8);
#pragma unroll
            for (int n = 0; n < 4; ++n) {
                int brow = n * 16 + (lane & 15);
                int bslot = (kk * 4 + (lane >> 4)) ^ (brow & 7);
                bf16x8 b = *(const bf16x8*)(lBs + brow * 64 + bslot * 8);
                acc[n] = __builtin_amdgcn_mfma_f32_16x16x32_bf16(a, b, acc[n], 0, 0, 0);
            }
        }
        __syncthreads();
    }

    const size_t grow0 = (size_t)rb * 64;
#pragma unroll
    for (int n = 0; n < 4; ++n) {
        int col = n * 16 + (lane & 15);
        int rowl = w * 16 + (lane >> 4) * 4;
#pragma unroll
        for (int r = 0; r < 4; ++r)
            partial[((size_t)chunk * 8192 + grow0 + rowl + r) * 64 + col] = acc[n][r];
    }
}

// MLP reduce + layer 2 + fused sqnorm. grid = 128 (64 rows each)
__global__ __launch_bounds__(256) void mlp2_kernel(const float* __restrict__ partial,
                                                   const float* __restrict__ b1,
                                                   const float* __restrict__ W2,
                                                   const float* __restrict__ b2,
                                                   float* __restrict__ embA,
                                                   float* __restrict__ embB,
                                                   float* __restrict__ sqA,
                                                   float* __restrict__ sqB) {
    const int rb = blockIdx.x;
    const int side = rb >> 6;
    const size_t grow0 = (size_t)rb * 64;
    const int r0 = (rb & 63) * 64;
    float* emb = side ? embB : embA;
    float* sq = side ? sqB : sqA;

    __shared__ float Hs[64][65];
    __shared__ float W2s[64][32];
    const int tid = threadIdx.x;

    {
        const float4* srcw = (const float4*)W2;
        float4* dst = (float4*)&W2s[0][0];
        for (int i = tid; i < 512; i += 256) dst[i] = srcw[i];
    }

    for (int v = tid; v < 1024; v += 256) {   // 64 rows x 16 float4
        int row = v >> 4, c4 = v & 15;
        float4 s = {0.f, 0.f, 0.f, 0.f};
#pragma unroll
        for (int c = 0; c < 4; ++c) {
            const float4 p = *(const float4*)(partial + ((size_t)c * 8192 + grow0 + row) * 64 + c4 * 4);
            s.x += p.x; s.y += p.y; s.z += p.z; s.w += p.w;
        }
        const float4 bb = *(const float4*)(b1 + c4 * 4);
        Hs[row][c4 * 4 + 0] = fmaxf(s.x + bb.x, 0.f);
        Hs[row][c4 * 4 + 1] = fmaxf(s.y + bb.y, 0.f);
        Hs[row][c4 * 4 + 2] = fmaxf(s.z + bb.z, 0.f);
        Hs[row][c4 * 4 + 3] = fmaxf(s.w + bb.w, 0.f);
    }
    __syncthreads();

    const int c2 = tid & 31, rg = tid >> 5;
    float acc2[8] = {};
    for (int k = 0; k < 64; ++k) {
        float wv = W2s[k][c2];
#pragma unroll
        for (int i = 0; i < 8; ++i) acc2[i] += Hs[rg * 8 + i][k] * wv;
    }
    float bb = b2[c2];
    float e[8];
#pragma unroll
    for (int i = 0; i < 8; ++i) {
        e[i] = fmaxf(acc2[i] + bb, 0.f);
        emb[(size_t)(r0 + rg * 8 + i) * 32 + c2] = e[i];
    }
#pragma unroll
    for (int i = 0; i < 8; ++i) {
        float v = e[i] * e[i];
#pragma unroll
        for (int off = 16; off > 0; off >>= 1) v += __shfl_xor(v, off, 32);
        if (c2 == 0) sq[r0 + rg * 8 + i] = v;
    }
}

// ---------------------------------------------------------------------------
// Fallback f32 GEMM (used only if ws too small)
template <bool TRANSB>
__global__ __launch_bounds__(256) void impute_gemm(const float* __restrict__ X,
                                                   const float* __restrict__ G,
                                                   const float* __restrict__ norm,
                                                   float* __restrict__ out) {
    __shared__ float As[8][128];
    __shared__ float Bs[8][128];
    const int tid = threadIdx.x;
    const int col_base = blockIdx.x * 128;
    const int row_base = blockIdx.y * 128;
    const int tx = tid & 15;
    const int ty = tid >> 4;
    float acc[8][8] = {};
    const int a_row = tid >> 1;
    const int a_k   = (tid & 1) * 4;
    for (int k0 = 0; k0 < G_B; k0 += 8) {
        {
            float4 av = *(const float4*)(X + (size_t)(row_base + a_row) * G_B + k0 + a_k);
            As[a_k + 0][a_row] = av.x;
            As[a_k + 1][a_row] = av.y;
            As[a_k + 2][a_row] = av.z;
            As[a_k + 3][a_row] = av.w;
        }
        if (!TRANSB) {
            const int bk = tid >> 5;
            const int bc = (tid & 31) * 4;
            float4 bv = {0.f, 0.f, 0.f, 0.f};
            if (col_base + bc < G_B)
                bv = *(const float4*)(G + (size_t)(k0 + bk) * G_B + col_base + bc);
            *(float4*)&Bs[bk][bc] = bv;
        } else {
            const int bj = tid >> 1;
            const int bk = (tid & 1) * 4;
            float4 bv = {0.f, 0.f, 0.f, 0.f};
            if (col_base + bj < G_B)
                bv = *(const float4*)(G + (size_t)(col_base + bj) * G_B + k0 + bk);
            Bs[bk + 0][bj] = bv.x;
            Bs[bk + 1][bj] = bv.y;
            Bs[bk + 2][bj] = bv.z;
            Bs[bk + 3][bj] = bv.w;
        }
        __syncthreads();
#pragma unroll
        for (int kk = 0; kk < 8; ++kk) {
            float4 a0 = *(const float4*)&As[kk][ty * 8];
            float4 a1 = *(const float4*)&As[kk][ty * 8 + 4];
            float4 b0 = *(const float4*)&Bs[kk][tx * 8];
            float4 b1 = *(const float4*)&Bs[kk][tx * 8 + 4];
            float a_[8] = {a0.x, a0.y, a0.z, a0.w, a1.x, a1.y, a1.z, a1.w};
            float b_[8] = {b0.x, b0.y, b0.z, b0.w, b1.x, b1.y, b1.z, b1.w};
#pragma unroll
            for (int i = 0; i < 8; ++i)
#pragma unroll
                for (int j = 0; j < 8; ++j) acc[i][j] += a_[i] * b_[j];
        }
        __syncthreads();
    }
    const int cg = col_base + tx * 8;
    if (cg < G_B) {
        float rn[8];
#pragma unroll
        for (int j = 0; j < 8; ++j) rn[j] = 1.0f / norm[cg + j];
#pragma unroll
        for (int i = 0; i < 8; ++i) {
            float4 o0 = {acc[i][0] * rn[0], acc[i][1] * rn[1], acc[i][2] * rn[2], acc[i][3] * rn[3]};
            float4 o1 = {acc[i][4] * rn[4], acc[i][5] * rn[5], acc[i][6] * rn[6], acc[i][7] * rn[7]};
            size_t o = (size_t)(row_base + ty * 8 + i) * G_B + cg;
            *(float4*)(out + o) = o0;
            *(float4*)(out + o + 4) = o1;
        }
    }
}

// Fallback MLP (f32)
#define MLP_TK 24
__global__ __launch_bounds__(256) void mlp_kernel(const float* __restrict__ xA,
                                                  const float* __restrict__ ximpA,
                                                  const float* __restrict__ ximpB,
                                                  const float* __restrict__ xB,
                                                  const float* __restrict__ W1,
                                                  const float* __restrict__ b1,
                                                  const float* __restrict__ W2,
                                                  const float* __restrict__ b2,
                                                  float* __restrict__ embA,
                                                  float* __restrict__ embB) {
    __shared__ float Xs[MLP_TK][64];
    __shared__ float Ws[MLP_TK][64];
    __shared__ float Hs[64][65];
    __shared__ float W2s[64][32];

    const int side = blockIdx.x >> 6;
    const int row0 = (blockIdx.x & 63) * 64;
    const float* srcL = side ? ximpB : xA;
    const float* srcR = side ? xB : ximpA;
    float* emb = side ? embB : embA;

    const int tid = threadIdx.x;
    {
        const float4* src = (const float4*)W2;
        float4* dst = (float4*)&W2s[0][0];
        for (int i = tid; i < 512; i += 256) dst[i] = src[i];
    }

    const int tx = tid & 15;
    const int ty = tid >> 4;
    float acc[4][4] = {};
    const int lrow = tid >> 2;
    const int lk6  = (tid & 3) * 6;

    for (int k0 = 0; k0 < 6000; k0 += MLP_TK) {
        const float* src = (k0 < 3000) ? srcL : srcR;
        const int kbase = (k0 < 3000) ? k0 : (k0 - 3000);
        {
            const float* p = src + (size_t)(row0 + lrow) * 3000 + kbase + lk6;
#pragma unroll
            for (int e = 0; e < 6; ++e) Xs[lk6 + e][lrow] = p[e];
        }
        {
#pragma unroll
            for (int e = 0; e < 6; ++e) {
                int idx = tid * 6 + e;
                int kk = idx >> 6, cc = idx & 63;
                Ws[kk][cc] = W1[(size_t)(k0 + kk) * 64 + cc];
            }
        }
        __syncthreads();
#pragma unroll
        for (int kk = 0; kk < MLP_TK; ++kk) {
            float4 a = *(const float4*)&Xs[kk][ty * 4];
            float4 wv = *(const float4*)&Ws[kk][tx * 4];
            float a_[4] = {a.x, a.y, a.z, a.w};
            float w_[4] = {wv.x, wv.y, wv.z, wv.w};
#pragma unroll
            for (int i = 0; i < 4; ++i)
#pragma unroll
                for (int j = 0; j < 4; ++j) acc[i][j] += a_[i] * w_[j];
        }
        __syncthreads();
    }

#pragma unroll
    for (int j = 0; j < 4; ++j) {
        float bj = b1[tx * 4 + j];
#pragma unroll
        for (int i = 0; i < 4; ++i) {
            float h = acc[i][j] + bj;
            Hs[ty * 4 + i][tx * 4 + j] = h > 0.f ? h : 0.f;
        }
    }
    __syncthreads();

    const int c2 = tid & 31;
    const int rg = tid >> 5;
    float acc2[8] = {};
    for (int k = 0; k < 64; ++k) {
        float wv = W2s[k][c2];
#pragma unroll
        for (int i = 0; i < 8; ++i) acc2[i] += Hs[rg * 8 + i][k] * wv;
    }
    float bb = b2[c2];
#pragma unroll
    for (int i = 0; i < 8; ++i) {
        float h = acc2[i] + bb;
        emb[(size_t)(row0 + rg * 8 + i) * 32 + c2] = h > 0.f ? h : 0.f;
    }
}

__global__ __launch_bounds__(256) void sqnorm_kernel(const float* __restrict__ emb,
                                                     float* __restrict__ sq) {
    int i = blockIdx.x * 256 + threadIdx.x;
    if (i >= N_A) return;
    const float4* e = (const float4*)(emb + (size_t)i * 32);
    float s = 0.f;
#pragma unroll
    for (int q = 0; q < 8; ++q) {
        float4 v = e[q];
        s += v.x * v.x + v.y * v.y + v.z * v.z + v.w * v.w;
    }
    sq[i] = s;
}

__global__ __launch_bounds__(256) void preds_kernel(const float* __restrict__ emb,
                                                    const float* __restrict__ Wc,
                                                    const float* __restrict__ bc,
                                                    float* __restrict__ out,
                                                    int ncls) {
    int idx = blockIdx.x * 256 + threadIdx.x;
    int row = idx / ncls, c = idx % ncls;
    const float* e = emb + (size_t)row * 32;
    float s = bc[c];
#pragma unroll
    for (int k = 0; k < 32; ++k) s += e[k] * Wc[k * ncls + c];
    out[idx] = s;
}

// ---------------------------------------------------------------------------
__global__ __launch_bounds__(256) void topk_kernel(const float* __restrict__ embQ,
                                                   const float* __restrict__ sqQ,
                                                   const float* __restrict__ embC,
                                                   const float* __restrict__ sqC,
                                                   int* __restrict__ nn) {
    int q = blockIdx.x;
    __shared__ float buf[4096];
    __shared__ float rv[256];
    __shared__ int ri[256];

    float4 qv[8];
    const float4* eq = (const float4*)(embQ + (size_t)q * 32);
#pragma unroll
    for (int t = 0; t < 8; ++t) qv[t] = eq[t];
    float sqq = sqQ[q];

    for (int j = threadIdx.x; j < 4096; j += 256) {
        const float4* ec = (const float4*)(embC + (size_t)j * 32);
        float dot = 0.f;
#pragma unroll
        for (int t = 0; t < 8; ++t) {
            float4 c = ec[t];
            dot += qv[t].x * c.x + qv[t].y * c.y + qv[t].z * c.z + qv[t].w * c.w;
        }
        buf[j] = sqq + sqC[j] - 2.f * dot;
    }
    __syncthreads();

    for (int r = 0; r < KNBR; ++r) {
        float best = FLT_MAX;
        int bi = 0x7fffffff;
        for (int j = threadIdx.x; j < 4096; j += 256) {
            float v = buf[j];
            if (v < best) { best = v; bi = j; }
        }
        rv[threadIdx.x] = best;
        ri[threadIdx.x] = bi;
        __syncthreads();
        for (int off = 128; off > 0; off >>= 1) {
            if (threadIdx.x < off) {
                float v2 = rv[threadIdx.x + off];
                int i2 = ri[threadIdx.x + off];
                if (v2 < rv[threadIdx.x] || (v2 == rv[threadIdx.x] && i2 < ri[threadIdx.x])) {
                    rv[threadIdx.x] = v2;
                    ri[threadIdx.x] = i2;
                }
            }
            __syncthreads();
        }
        if (threadIdx.x == 0) {
            nn[(size_t)q * KNBR + r] = ri[0];
            buf[ri[0]] = FLT_MAX;
        }
        __syncthreads();
    }
}

// ---------------------------------------------------------------------------
__global__ __launch_bounds__(256) void predloss_kernel(const int* __restrict__ nn,
                                                       const float* __restrict__ ximp,
                                                       const float* __restrict__ xtrue,
                                                       float* __restrict__ partial) {
    int q = blockIdx.x;
    __shared__ int nns[KNBR];
    __shared__ float red[256];
    if (threadIdx.x < KNBR) nns[threadIdx.x] = nn[(size_t)q * KNBR + threadIdx.x];
    __syncthreads();

    int nr[KNBR];
#pragma unroll
    for (int t = 0; t < KNBR; ++t) nr[t] = nns[t];

    const float inv = 1.0f / KNBR;
    float sse = 0.f;
    for (int v = threadIdx.x; v < 750; v += 256) {
        float4 acc = {0.f, 0.f, 0.f, 0.f};
#pragma unroll
        for (int t = 0; t < KNBR; ++t) {
            const float4 w = *(const float4*)(ximp + (size_t)nr[t] * 3000 + v * 4);
            acc.x += w.x; acc.y += w.y; acc.z += w.z; acc.w += w.w;
        }
        const float4 xt = *(const float4*)(xtrue + (size_t)q * 3000 + v * 4);
        float dx = acc.x * inv - xt.x;
        float dy = acc.y * inv - xt.y;
        float dz = acc.z * inv - xt.z;
        float dw = acc.w * inv - xt.w;
        sse += dx * dx + dy * dy + dz * dz + dw * dw;
    }
    red[threadIdx.x] = sse;
    __syncthreads();
    for (int off = 128; off > 0; off >>= 1) {
        if (threadIdx.x < off) red[threadIdx.x] += red[threadIdx.x + off];
        __syncthreads();
    }
    if (threadIdx.x == 0) partial[q] = red[0];
}

__global__ __launch_bounds__(256) void loss_final_kernel(const float* __restrict__ pA,
                                                         const float* __restrict__ pB,
                                                         float* __restrict__ out) {
    __shared__ double red[256];
    double sa = 0.0, sb = 0.0;
    for (int i = threadIdx.x; i < 4096; i += 256) {
        sa += (double)pA[i];
        sb += (double)pB[i];
    }
    red[threadIdx.x] = sa;
    __syncthreads();
    for (int off = 128; off > 0; off >>= 1) {
        if (threadIdx.x < off) red[threadIdx.x] += red[threadIdx.x + off];
        __syncthreads();
    }
    double totA = red[0];
    __syncthreads();
    red[threadIdx.x] = sb;
    __syncthreads();
    for (int off = 128; off > 0; off >>= 1) {
        if (threadIdx.x < off) red[threadIdx.x] += red[threadIdx.x + off];
        __syncthreads();
    }
    if (threadIdx.x == 0) {
        double denom = 4096.0 * 3000.0;
        out[0] = (float)(totA / denom + red[0] / denom);
    }
}

// ---------------------------------------------------------------------------
extern "C" void kernel_launch(void* const* d_in, const int* in_sizes, int n_in,
                              void* d_out, int out_size, void* d_ws, size_t ws_size,
                              hipStream_t stream) {
    const float* x_A = (const float*)d_in[0];
    const float* x_B = (const float*)d_in[1];
    const float* G   = (const float*)d_in[2];
    const float* W1  = (const float*)d_in[3];
    const float* b1  = (const float*)d_in[4];
    const float* W2  = (const float*)d_in[5];
    const float* b2  = (const float*)d_in[6];
    const float* WcA = (const float*)d_in[7];
    const float* bcA = (const float*)d_in[8];
    const float* WcB = (const float*)d_in[9];
    const float* bcB = (const float*)d_in[10];

    float* outp = (float*)d_out;

    size_t off = 0;
    char* base = (char*)d_ws;
    auto carve = [&](size_t bytes) -> void* {
        void* p = base + off;
        off = (off + bytes + 255) & ~(size_t)255;
        return p;
    };
    float* ximpA = (float*)carve((size_t)N_A * G_B * 4);
    float* ximpB = (float*)carve((size_t)N_B * G_A * 4);
    float* normA = (float*)carve(G_A * 4);
    float* normB = (float*)carve(G_B * 4);
    float* colpart = (float*)carve(25 * G_B * 4);
    float* embA = (float*)carve((size_t)N_A * 32 * 4);
    float* embB = (float*)carve((size_t)N_B * 32 * 4);
    float* sqA = (float*)carve(N_A * 4);
    float* sqB = (float*)carve(N_B * 4);
    float* partA = (float*)carve(N_A * 4);
    float* partB = (float*)carve(N_B * 4);
    int* nnA = (int*)carve((size_t)N_A * KNBR * 4);
    int* nnB = (int*)carve((size_t)N_B * KNBR * 4);
    u16* xAbf = (u16*)carve((size_t)N_A * KPAD * 2);
    u16* xBbf = (u16*)carve((size_t)N_B * KPAD * 2);
    u16* Gbf  = (u16*)carve((size_t)KPAD * KPAD * 2);
    u16* Gtbf = (u16*)carve((size_t)KPAD * KPAD * 2);
    size_t r2_needed = off;
    u16* ximpAbf = (u16*)carve((size_t)N_A * KPAD * 2);
    u16* ximpBbf = (u16*)carve((size_t)N_B * KPAD * 2);
    u16* W1tbf   = (u16*)carve((size_t)64 * KMLP * 2);
    float* mlppart = (float*)carve((size_t)4 * 8192 * 64 * 4);
    size_t full_needed = off;

    const bool use_mfma = (ws_size >= r2_needed);
    const bool use_mlp_mfma = (ws_size >= full_needed);

    // 1) normalizers
    row_sum_kernel<<<G_A, 256, 0, stream>>>(G, normA);
    col_partial_kernel<<<dim3(12, 25), 256, 0, stream>>>(G, colpart);
    col_final_kernel<<<12, 256, 0, stream>>>(colpart, normB);

    // 2) imputation GEMMs (+ bf16 copies)
    if (use_mfma && use_mlp_mfma) {
        convert_pad_kernel<<<(N_A * (KPAD / 8)) / 256, 256, 0, stream>>>(x_A, xAbf, N_A, G_A, KPAD);
        convert_pad_kernel<<<(N_B * (KPAD / 8)) / 256, 256, 0, stream>>>(x_B, xBbf, N_B, G_B, KPAD);
        convert_pad_kernel<<<(KPAD * (KPAD / 8)) / 256, 256, 0, stream>>>(G, Gbf, G_A, G_B, KPAD);
        transpose_convert_kernel<<<dim3(96, 96), 256, 0, stream>>>(G, Gtbf);
        w1t_kernel<<<(64 * KMLP) / 256, 256, 0, stream>>>(W1, W1tbf);

        dim3 ggrid(KPAD / 128, N_A / 128);
        mfma_impute_gemm<<<ggrid, 256, 0, stream>>>(xAbf, Gtbf, normB, ximpA, ximpAbf);
        mfma_impute_gemm<<<ggrid, 256, 0, stream>>>(xBbf, Gbf, normA, ximpB, ximpBbf);

        // 3) MLP via MFMA + K-split
        mlp1_kernel<<<dim3(4, 128), 256, 0, stream>>>(xAbf, ximpAbf, ximpBbf, xBbf, W1tbf, mlppart);
        mlp2_kernel<<<128, 256, 0, stream>>>(mlppart, b1, W2, b2, embA, embB, sqA, sqB);
    } else {
        dim3 ggrid(24, 32);
        impute_gemm<false><<<ggrid, 256, 0, stream>>>(x_A, G, normB, ximpA);
        impute_gemm<true><<<ggrid, 256, 0, stream>>>(x_B, G, normA, ximpB);
        mlp_kernel<<<128, 256, 0, stream>>>(x_A, ximpA, ximpB, x_B, W1, b1, W2, b2, embA, embB);
        sqnorm_kernel<<<16, 256, 0, stream>>>(embA, sqA);
        sqnorm_kernel<<<16, 256, 0, stream>>>(embB, sqB);
    }

    // 5) class predictions -> d_out
    preds_kernel<<<(N_A * NCA) / 256, 256, 0, stream>>>(embA, WcA, bcA, outp, NCA);
    preds_kernel<<<(N_B * NCB) / 256, 256, 0, stream>>>(embB, WcB, bcB, outp + (size_t)N_A * NCA, NCB);

    // 6) top-20 neighbors
    topk_kernel<<<N_A, 256, 0, stream>>>(embA, sqA, embB, sqB, nnA);
    topk_kernel<<<N_B, 256, 0, stream>>>(embB, sqB, embA, sqA, nnB);

    // 7) fused gather-mean + MSE partials
    predloss_kernel<<<N_A, 256, 0, stream>>>(nnA, ximpB, x_A, partA);
    predloss_kernel<<<N_B, 256, 0, stream>>>(nnB, ximpA, x_B, partB);

    // 8) final loss
    loss_final_kernel<<<1, 256, 0, stream>>>(partA, partB, outp + (size_t)N_A * NCA + (size_t)N_B * NCB);

    (void)in_sizes; (void)n_in; (void)out_size;
}